// Round 5
// baseline (260.104 us; speedup 1.0000x reference)
//
#include <hip/hip_runtime.h>

typedef float f32x4 __attribute__((ext_vector_type(4)));
typedef short s16x8 __attribute__((ext_vector_type(8)));
typedef unsigned short u16;

#define B_ 2
#define S_ 2048
#define HID 1536
#define NQ_ 24
#define NKV_ 4
#define HD 64
#define NTOK (B_*S_)
#define QKVN ((NQ_+2*NKV_)*HD)   // 2048

__device__ __forceinline__ float bf2f(u16 u) {
  unsigned int x = ((unsigned int)u) << 16;
  float f; __builtin_memcpy(&f, &x, 4); return f;
}
__device__ __forceinline__ u16 f2bf(float f) {
  unsigned int u; __builtin_memcpy(&u, &f, 4);
  u += 0x7fffu + ((u >> 16) & 1u);
  return (u16)(u >> 16);
}

// ---------------- dtype-adaptive input conversion -> bf16 ----------------
// R1/R2-vs-R3 delta proved inputs are fp32. Probe kept as insurance.
__global__ __launch_bounds__(256) void k_cvt(const void* __restrict__ src,
                                             u16* __restrict__ dst, int n4,
                                             const unsigned int* __restrict__ probe) {
  int i = blockIdx.x * 256 + threadIdx.x;   // units of 4 elements
  if (i >= n4) return;
  if (probe[0] == 0x3F800000u) {            // fp32 input
    f32x4 v = ((const f32x4*)src)[i];
    unsigned long long pk =
        (unsigned long long)f2bf(v[0]) |
        ((unsigned long long)f2bf(v[1]) << 16) |
        ((unsigned long long)f2bf(v[2]) << 32) |
        ((unsigned long long)f2bf(v[3]) << 48);
    *(unsigned long long*)(dst + (size_t)i*4) = pk;
  } else {                                   // already bf16: copy 8B
    *(unsigned long long*)(dst + (size_t)i*4) = ((const unsigned long long*)src)[i];
  }
}

// ---------------- RMSNorm ----------------
__global__ __launch_bounds__(256) void k_rmsnorm(const u16* __restrict__ x,
                                                 const u16* __restrict__ g,
                                                 u16* __restrict__ xn) {
  int row = blockIdx.x;
  const u16* xr = x + (size_t)row * HID;
  int t = threadIdx.x;
  float v[6];
  float ss = 0.f;
#pragma unroll
  for (int i = 0; i < 6; i++) { v[i] = bf2f(xr[t + 256*i]); ss += v[i]*v[i]; }
#pragma unroll
  for (int off = 1; off < 64; off <<= 1) ss += __shfl_xor(ss, off);
  __shared__ float red[4];
  if ((t & 63) == 0) red[t >> 6] = ss;
  __syncthreads();
  float tot = red[0] + red[1] + red[2] + red[3];
  float rs = rsqrtf(tot * (1.f/HID) + 1e-6f);
  u16* xo = xn + (size_t)row * HID;
#pragma unroll
  for (int i = 0; i < 6; i++) xo[t + 256*i] = f2bf(v[i] * rs * bf2f(g[t + 256*i]));
}

// ---------------- GEMM C[M][N] = A[M][K] @ W[N][K]^T ----------------
// m97-recipe structure. F32OUT selects fp32 output + fp32 residual (final proj)
// vs bf16 output, no residual (QKV proj). R4 lesson: d_out is FP32 (reference
// output dtype), so the last GEMM must store float, not packed bf16.
template <bool F32OUT>
__global__ __launch_bounds__(256) void k_gemm_bt(const u16* __restrict__ A,
                                                 const u16* __restrict__ W,
                                                 void* __restrict__ Cv,
                                                 const float* __restrict__ resid,
                                                 int M, int N, int K) {
  __shared__ __align__(16) u16 As[128*32];
  __shared__ __align__(16) u16 Bs[128*32];
  int m0 = blockIdx.y * 128, n0 = blockIdx.x * 128;
  int tid = threadIdx.x;
  int w = tid >> 6, l = tid & 63;
  int wr = w >> 1, wc = w & 1;
  int c = l & 15, g = l >> 4;
  f32x4 acc[4][4] = {};
  const u16* Ag = A + (size_t)(m0 + w*32 + (l>>2))*K + (l&3)*8;
  const u16* Wg = W + (size_t)(n0 + w*32 + (l>>2))*K + (l&3)*8;
  u16* AsW = As + w*32*32;
  u16* BsW = Bs + w*32*32;
  for (int k0 = 0; k0 < K; k0 += 32) {
    __builtin_amdgcn_global_load_lds((const __attribute__((address_space(1))) void*)(Ag + k0),
                                     (__attribute__((address_space(3))) void*)AsW, 16, 0, 0);
    __builtin_amdgcn_global_load_lds((const __attribute__((address_space(1))) void*)(Ag + k0 + (size_t)16*K),
                                     (__attribute__((address_space(3))) void*)(AsW + 16*32), 16, 0, 0);
    __builtin_amdgcn_global_load_lds((const __attribute__((address_space(1))) void*)(Wg + k0),
                                     (__attribute__((address_space(3))) void*)BsW, 16, 0, 0);
    __builtin_amdgcn_global_load_lds((const __attribute__((address_space(1))) void*)(Wg + k0 + (size_t)16*K),
                                     (__attribute__((address_space(3))) void*)(BsW + 16*32), 16, 0, 0);
    __syncthreads();
    s16x8 af[4], bq[4];
#pragma unroll
    for (int mt = 0; mt < 4; mt++) af[mt] = *(const s16x8*)(As + (wr*64 + mt*16 + c)*32 + g*8);
#pragma unroll
    for (int nt = 0; nt < 4; nt++) bq[nt] = *(const s16x8*)(Bs + (wc*64 + nt*16 + c)*32 + g*8);
#pragma unroll
    for (int mt = 0; mt < 4; mt++)
#pragma unroll
      for (int nt = 0; nt < 4; nt++)
        acc[mt][nt] = __builtin_amdgcn_mfma_f32_16x16x32_bf16(af[mt], bq[nt], acc[mt][nt], 0, 0, 0);
    __syncthreads();
  }
#pragma unroll
  for (int mt = 0; mt < 4; mt++)
#pragma unroll
    for (int nt = 0; nt < 4; nt++)
#pragma unroll
      for (int r = 0; r < 4; r++) {
        int m = m0 + wr*64 + mt*16 + g*4 + r;
        int n = n0 + wc*64 + nt*16 + c;
        size_t off = (size_t)m*N + n;
        float vv = acc[mt][nt][r];
        if (F32OUT) {
          ((float*)Cv)[off] = vv + resid[off];
        } else {
          ((u16*)Cv)[off] = f2bf(vv);
        }
      }
}

// ---------------- RoPE + scatter q,k ----------------
__global__ __launch_bounds__(256) void k_rope(const u16* __restrict__ qkv,
                                              u16* __restrict__ q,
                                              u16* __restrict__ k,
                                              const int* __restrict__ spp) {
  int idx = blockIdx.x * 256 + threadIdx.x;     // (tok*28 + h)*32 + p
  int p = idx & 31;
  int h = (idx >> 5) % 28;
  int tok = idx / 896;
  int s = tok & (S_ - 1);
  int b = tok >> 11;
  float t = (float)(spp[0] + s);
  float inv = powf(10000.f, -(float)p * (1.f/32.f));
  float fr = t * inv;
  float sn, cs;
  sincosf(fr, &sn, &cs);
  int col = (h < NQ_) ? h*64 + 2*p : HID + (h - NQ_)*64 + 2*p;
  unsigned int pr = *(const unsigned int*)(qkv + (size_t)tok*QKVN + col);
  float x1 = bf2f((u16)(pr & 0xffff));
  float x2 = bf2f((u16)(pr >> 16));
  float y1 = x1*cs - x2*sn;
  float y2 = x2*cs + x1*sn;
  unsigned int outp = (unsigned int)f2bf(y1) | ((unsigned int)f2bf(y2) << 16);
  if (h < NQ_) {
    *(unsigned int*)(q + (((size_t)(b*NQ_ + h))*S_ + s)*64 + 2*p) = outp;
  } else {
    *(unsigned int*)(k + (((size_t)(b*NKV_ + (h - NQ_)))*S_ + s)*64 + 2*p) = outp;
  }
}

// ---------------- V transpose: vt[b][hk][d][s] ----------------
__global__ __launch_bounds__(256) void k_vt(const u16* __restrict__ qkv,
                                            u16* __restrict__ vt) {
  __shared__ u16 tile[64][65];
  int blk = blockIdx.x;
  int st = blk & 31;
  int hk = (blk >> 5) & 3;
  int b = blk >> 7;
  int s0 = st * 64;
#pragma unroll
  for (int i = 0; i < 16; i++) {
    int ii = threadIdx.x + i*256;
    int r = ii >> 6, cc = ii & 63;
    tile[r][cc] = qkv[((size_t)(b*S_) + s0 + r)*QKVN + (NQ_+NKV_)*64 + hk*64 + cc];
  }
  __syncthreads();
#pragma unroll
  for (int i = 0; i < 16; i++) {
    int ii = threadIdx.x + i*256;
    int d = ii >> 6, s = ii & 63;
    vt[((size_t)(b*NKV_ + hk)*64 + d)*S_ + s0 + s] = tile[s][d];
  }
}

// ---------------- Flash attention, one wave per (b,h,64-query tile) ----------------
// S^T = K@Q^T (per-column softmax stats, 2 shuffles); P^T re-enters PV as the
// B-operand via wave-local LDS (m120-verified round-trip), TBAA-fenced.
// R3==R4 bit-identical absmax certified this kernel against the scalar reference.
__global__ __launch_bounds__(64, 1) void k_attn(const u16* __restrict__ q,
                                                const u16* __restrict__ k,
                                                const u16* __restrict__ vt,
                                                u16* __restrict__ ao,
                                                const int* __restrict__ spp) {
  __shared__ __align__(16) u16 Pt[64*72];
  int blk = blockIdx.x;
  int qb = blk & 31;
  int h = (blk >> 5) % NQ_;
  int b = blk / (32*NQ_);
  int q0 = qb * 64;
  int hk = h / (NQ_/NKV_);
  int l = threadIdx.x;
  int c = l & 15, g = l >> 4;
  int sp = spp[0];
  const u16* qptr = q + ((size_t)(b*NQ_ + h))*S_*64;
  const u16* kptr = k + ((size_t)(b*NKV_ + hk))*S_*64;
  const u16* vptr = vt + ((size_t)(b*NKV_ + hk))*64*S_;

  s16x8 qf[4][2];
#pragma unroll
  for (int qt = 0; qt < 4; qt++)
#pragma unroll
    for (int ks = 0; ks < 2; ks++)
      qf[qt][ks] = *(const s16x8*)(qptr + (size_t)(q0 + qt*16 + c)*64 + ks*32 + g*8);

  f32x4 o[4][4] = {};          // o[dt][qt]: O^T accum, row=d col=q
  float m_run[4], l_run[4];
#pragma unroll
  for (int i = 0; i < 4; i++) { m_run[i] = -1e30f; l_run[i] = 0.f; }

  int lo = sp + q0 - 256; if (lo < 0) lo = 0;
  int hi = sp + q0 + 63;  if (hi > S_ - 1) hi = S_ - 1;
  for (int kt = (lo >> 6); kt <= (hi >> 6); kt++) {
    s16x8 kf[4][2];
#pragma unroll
    for (int km = 0; km < 4; km++)
#pragma unroll
      for (int ks = 0; ks < 2; ks++)
        kf[km][ks] = *(const s16x8*)(kptr + (size_t)(kt*64 + km*16 + c)*64 + ks*32 + g*8);
    f32x4 sa[4][4] = {};       // sa[km][qt]: S^T tile, row=key col=query
#pragma unroll
    for (int km = 0; km < 4; km++)
#pragma unroll
      for (int qt = 0; qt < 4; qt++) {
        sa[km][qt] = __builtin_amdgcn_mfma_f32_16x16x32_bf16(kf[km][0], qf[qt][0], sa[km][qt], 0, 0, 0);
        sa[km][qt] = __builtin_amdgcn_mfma_f32_16x16x32_bf16(kf[km][1], qf[qt][1], sa[km][qt], 0, 0, 0);
      }
#pragma unroll
    for (int qt = 0; qt < 4; qt++) {
      int qi = q0 + qt*16 + c;
      int pos = sp + qi;
      float mx = -1e30f;
#pragma unroll
      for (int km = 0; km < 4; km++)
#pragma unroll
        for (int r = 0; r < 4; r++) {
          int key = kt*64 + km*16 + g*4 + r;
          float sv = sa[km][qt][r] * 0.125f;
          bool valid = (key <= pos) && (key >= pos - 256);
          sv = valid ? sv : -1e30f;
          sa[km][qt][r] = sv;
          mx = fmaxf(mx, sv);
        }
      mx = fmaxf(mx, __shfl_xor(mx, 16));
      mx = fmaxf(mx, __shfl_xor(mx, 32));
      float mnew = fmaxf(m_run[qt], mx);
      float alpha = __expf(m_run[qt] - mnew);
      m_run[qt] = mnew;
      float rsum = 0.f;
#pragma unroll
      for (int km = 0; km < 4; km++)
#pragma unroll
        for (int r = 0; r < 4; r++) {
          float sv = sa[km][qt][r];
          float pv = (sv > -1e29f) ? __expf(sv - mnew) : 0.f;
          sa[km][qt][r] = pv;
          rsum += pv;
        }
      rsum += __shfl_xor(rsum, 16);
      rsum += __shfl_xor(rsum, 32);
      l_run[qt] = l_run[qt]*alpha + rsum;
#pragma unroll
      for (int dt = 0; dt < 4; dt++) {
        o[dt][qt][0] *= alpha; o[dt][qt][1] *= alpha;
        o[dt][qt][2] *= alpha; o[dt][qt][3] *= alpha;
      }
    }
    // Fence: previous iteration's Pt reads must complete before overwrite.
    __syncthreads();
    // P^T -> LDS as Pt[q][key] (4 consecutive keys per lane -> b64 write)
#pragma unroll
    for (int km = 0; km < 4; km++)
#pragma unroll
      for (int qt = 0; qt < 4; qt++) {
        unsigned long long pk =
            (unsigned long long)f2bf(sa[km][qt][0]) |
            ((unsigned long long)f2bf(sa[km][qt][1]) << 16) |
            ((unsigned long long)f2bf(sa[km][qt][2]) << 32) |
            ((unsigned long long)f2bf(sa[km][qt][3]) << 48);
        *(unsigned long long*)(Pt + (qt*16 + c)*72 + km*16 + g*4) = pk;
      }
    // Fence: Pt writes visible before the typed-differently reads below.
    __syncthreads();
    // PV: O^T += V^T @ P^T
#pragma unroll
    for (int ks = 0; ks < 2; ks++) {
      s16x8 vf[4];
#pragma unroll
      for (int dt = 0; dt < 4; dt++)
        vf[dt] = *(const s16x8*)(vptr + (size_t)(dt*16 + c)*S_ + kt*64 + ks*32 + g*8);
#pragma unroll
      for (int qt = 0; qt < 4; qt++) {
        s16x8 pf = *(const s16x8*)(Pt + (qt*16 + c)*72 + ks*32 + g*8);
#pragma unroll
        for (int dt = 0; dt < 4; dt++)
          o[dt][qt] = __builtin_amdgcn_mfma_f32_16x16x32_bf16(vf[dt], pf, o[dt][qt], 0, 0, 0);
      }
    }
  }
#pragma unroll
  for (int qt = 0; qt < 4; qt++) {
    float inv = 1.f / l_run[qt];
    int qi = q0 + qt*16 + c;
#pragma unroll
    for (int dt = 0; dt < 4; dt++)
#pragma unroll
      for (int r = 0; r < 4; r++) {
        int d = dt*16 + g*4 + r;
        ao[((size_t)(b*S_) + qi)*HID + h*64 + d] = f2bf(o[dt][qt][r] * inv);
      }
  }
}

extern "C" void kernel_launch(void* const* d_in, const int* in_sizes, int n_in,
                              void* d_out, int out_size, void* d_ws, size_t ws_size,
                              hipStream_t stream) {
  const void*  x_raw    = d_in[0];
  const void*  g_raw    = d_in[1];
  const void*  wqkv_raw = d_in[2];
  const void*  wout_raw = d_in[3];
  const int*   spp      = (const int*)d_in[4];
  const float* x_f32    = (const float*)d_in[0];              // residual (fp32 input)
  const unsigned int* probe = (const unsigned int*)d_in[1];   // norm_scale[0] == 1.0
  char* ws = (char*)d_ws;
  // workspace layout (bytes), ~69.7 MB total
  u16* xb    = (u16*)(ws);                    // 12,582,912  x as bf16
  u16* wqkvb = (u16*)(ws + 12582912);         //  6,291,456
  u16* woutb = (u16*)(ws + 18874368);         //  4,718,592
  u16* gb    = (u16*)(ws + 23592960);         //      4,096 (3,072 used)
  u16* xn    = (u16*)(ws + 23597056);         // 12,582,912
  u16* qkv   = (u16*)(ws + 36179968);         // 16,777,216
  u16* qbuf  = (u16*)(ws + 52957184);         // 12,582,912
  u16* kbuf  = (u16*)(ws + 65540096);         //  2,097,152
  u16* vtb   = (u16*)(ws + 67637248);         //  2,097,152  (end 69,734,400)
  u16* attn  = xn;                            // aliases xn (dead after GEMM1)

  const int nx = NTOK*HID, nwq = QKVN*HID, nwo = HID*HID, ng = HID;
  k_cvt<<<(nx/4 + 255)/256, 256, 0, stream>>>(x_raw, xb, nx/4, probe);
  k_cvt<<<(nwq/4 + 255)/256, 256, 0, stream>>>(wqkv_raw, wqkvb, nwq/4, probe);
  k_cvt<<<(nwo/4 + 255)/256, 256, 0, stream>>>(wout_raw, woutb, nwo/4, probe);
  k_cvt<<<(ng/4 + 255)/256, 256, 0, stream>>>(g_raw, gb, ng/4, probe);

  k_rmsnorm<<<NTOK, 256, 0, stream>>>(xb, gb, xn);
  k_gemm_bt<false><<<dim3(QKVN/128, NTOK/128), 256, 0, stream>>>(xn, wqkvb, qkv, nullptr, NTOK, QKVN, HID);
  k_rope<<<(NTOK*28*32)/256, 256, 0, stream>>>(qkv, qbuf, kbuf, spp);
  k_vt<<<B_*NKV_*(S_/64), 256, 0, stream>>>(qkv, vtb);
  k_attn<<<B_*NQ_*(S_/64), 64, 0, stream>>>(qbuf, kbuf, vtb, attn, spp);
  k_gemm_bt<true><<<dim3(HID/128, NTOK/128), 256, 0, stream>>>(attn, woutb, d_out, x_f32, NTOK, HID, HID);
}

// Round 6
// 257.628 us; speedup vs baseline: 1.0096x; 1.0096x over previous
//
#include <hip/hip_runtime.h>

typedef float f32x4 __attribute__((ext_vector_type(4)));
typedef short s16x8 __attribute__((ext_vector_type(8)));
typedef unsigned short u16;

#define B_ 2
#define S_ 2048
#define HID 1536
#define NQ_ 24
#define NKV_ 4
#define HD 64
#define NTOK (B_*S_)
#define QKVN ((NQ_+2*NKV_)*HD)   // 2048

__device__ __forceinline__ float bf2f(u16 u) {
  unsigned int x = ((unsigned int)u) << 16;
  float f; __builtin_memcpy(&f, &x, 4); return f;
}
__device__ __forceinline__ u16 f2bf(float f) {
  unsigned int u; __builtin_memcpy(&u, &f, 4);
  u += 0x7fffu + ((u >> 16) & 1u);
  return (u16)(u >> 16);
}
__device__ __forceinline__ unsigned long long pk4bf(float a, float b, float c, float d) {
  return (unsigned long long)f2bf(a) |
         ((unsigned long long)f2bf(b) << 16) |
         ((unsigned long long)f2bf(c) << 32) |
         ((unsigned long long)f2bf(d) << 48);
}

// ---------------- fp32 -> bf16 weight conversion ----------------
__global__ __launch_bounds__(256) void k_cvt(const float* __restrict__ src,
                                             u16* __restrict__ dst, int n4) {
  int i = blockIdx.x * 256 + threadIdx.x;   // units of 4 elements
  if (i >= n4) return;
  f32x4 v = ((const f32x4*)src)[i];
  *(unsigned long long*)(dst + (size_t)i*4) = pk4bf(v[0], v[1], v[2], v[3]);
}

// ---------------- RMSNorm (fused fp32 read -> bf16 write) ----------------
__global__ __launch_bounds__(384) void k_rmsnorm(const float* __restrict__ x,
                                                 const float* __restrict__ g,
                                                 u16* __restrict__ xn) {
  int row = blockIdx.x;
  int t = threadIdx.x;
  f32x4 v = ((const f32x4*)(x + (size_t)row * HID))[t];
  float ss = v[0]*v[0] + v[1]*v[1] + v[2]*v[2] + v[3]*v[3];
#pragma unroll
  for (int off = 1; off < 64; off <<= 1) ss += __shfl_xor(ss, off);
  __shared__ float red[6];
  if ((t & 63) == 0) red[t >> 6] = ss;
  __syncthreads();
  float tot = red[0] + red[1] + red[2] + red[3] + red[4] + red[5];
  float rs = rsqrtf(tot * (1.f/HID) + 1e-6f);
  f32x4 gv = ((const f32x4*)g)[t];
  ((unsigned long long*)(xn + (size_t)row * HID))[t] =
      pk4bf(v[0]*rs*gv[0], v[1]*rs*gv[1], v[2]*rs*gv[2], v[3]*rs*gv[3]);
}

// ---------------- GEMM C[M][N] = A[M][K] @ W[N][K]^T ----------------
// m97-recipe. F32OUT: fp32 output + fp32 residual (final proj); else bf16 out.
template <bool F32OUT>
__global__ __launch_bounds__(256) void k_gemm_bt(const u16* __restrict__ A,
                                                 const u16* __restrict__ W,
                                                 void* __restrict__ Cv,
                                                 const float* __restrict__ resid,
                                                 int M, int N, int K) {
  __shared__ __align__(16) u16 As[128*32];
  __shared__ __align__(16) u16 Bs[128*32];
  int m0 = blockIdx.y * 128, n0 = blockIdx.x * 128;
  int tid = threadIdx.x;
  int w = tid >> 6, l = tid & 63;
  int wr = w >> 1, wc = w & 1;
  int c = l & 15, g = l >> 4;
  f32x4 acc[4][4] = {};
  const u16* Ag = A + (size_t)(m0 + w*32 + (l>>2))*K + (l&3)*8;
  const u16* Wg = W + (size_t)(n0 + w*32 + (l>>2))*K + (l&3)*8;
  u16* AsW = As + w*32*32;
  u16* BsW = Bs + w*32*32;
  for (int k0 = 0; k0 < K; k0 += 32) {
    __builtin_amdgcn_global_load_lds((const __attribute__((address_space(1))) void*)(Ag + k0),
                                     (__attribute__((address_space(3))) void*)AsW, 16, 0, 0);
    __builtin_amdgcn_global_load_lds((const __attribute__((address_space(1))) void*)(Ag + k0 + (size_t)16*K),
                                     (__attribute__((address_space(3))) void*)(AsW + 16*32), 16, 0, 0);
    __builtin_amdgcn_global_load_lds((const __attribute__((address_space(1))) void*)(Wg + k0),
                                     (__attribute__((address_space(3))) void*)BsW, 16, 0, 0);
    __builtin_amdgcn_global_load_lds((const __attribute__((address_space(1))) void*)(Wg + k0 + (size_t)16*K),
                                     (__attribute__((address_space(3))) void*)(BsW + 16*32), 16, 0, 0);
    __syncthreads();
    s16x8 af[4], bq[4];
#pragma unroll
    for (int mt = 0; mt < 4; mt++) af[mt] = *(const s16x8*)(As + (wr*64 + mt*16 + c)*32 + g*8);
#pragma unroll
    for (int nt = 0; nt < 4; nt++) bq[nt] = *(const s16x8*)(Bs + (wc*64 + nt*16 + c)*32 + g*8);
#pragma unroll
    for (int mt = 0; mt < 4; mt++)
#pragma unroll
      for (int nt = 0; nt < 4; nt++)
        acc[mt][nt] = __builtin_amdgcn_mfma_f32_16x16x32_bf16(af[mt], bq[nt], acc[mt][nt], 0, 0, 0);
    __syncthreads();
  }
#pragma unroll
  for (int mt = 0; mt < 4; mt++)
#pragma unroll
    for (int nt = 0; nt < 4; nt++)
#pragma unroll
      for (int r = 0; r < 4; r++) {
        int m = m0 + wr*64 + mt*16 + g*4 + r;
        int n = n0 + wc*64 + nt*16 + c;
        size_t off = (size_t)m*N + n;
        float vv = acc[mt][nt][r];
        if (F32OUT) {
          ((float*)Cv)[off] = vv + resid[off];
        } else {
          ((u16*)Cv)[off] = f2bf(vv);
        }
      }
}

// ---------------- RoPE + scatter q,k ----------------
__global__ __launch_bounds__(256) void k_rope(const u16* __restrict__ qkv,
                                              u16* __restrict__ q,
                                              u16* __restrict__ k,
                                              const int* __restrict__ spp) {
  int idx = blockIdx.x * 256 + threadIdx.x;     // (tok*28 + h)*32 + p
  int p = idx & 31;
  int h = (idx >> 5) % 28;
  int tok = idx / 896;
  int s = tok & (S_ - 1);
  int b = tok >> 11;
  float t = (float)(spp[0] + s);
  float inv = powf(10000.f, -(float)p * (1.f/32.f));
  float fr = t * inv;
  float sn, cs;
  sincosf(fr, &sn, &cs);
  int col = (h < NQ_) ? h*64 + 2*p : HID + (h - NQ_)*64 + 2*p;
  unsigned int pr = *(const unsigned int*)(qkv + (size_t)tok*QKVN + col);
  float x1 = bf2f((u16)(pr & 0xffff));
  float x2 = bf2f((u16)(pr >> 16));
  float y1 = x1*cs - x2*sn;
  float y2 = x2*cs + x1*sn;
  unsigned int outp = (unsigned int)f2bf(y1) | ((unsigned int)f2bf(y2) << 16);
  if (h < NQ_) {
    *(unsigned int*)(q + (((size_t)(b*NQ_ + h))*S_ + s)*64 + 2*p) = outp;
  } else {
    *(unsigned int*)(k + (((size_t)(b*NKV_ + (h - NQ_)))*S_ + s)*64 + 2*p) = outp;
  }
}

// ---------------- V transpose: vt[b][hk][d][s] ----------------
__global__ __launch_bounds__(256) void k_vt(const u16* __restrict__ qkv,
                                            u16* __restrict__ vt) {
  __shared__ u16 tile[64][65];
  int blk = blockIdx.x;
  int st = blk & 31;
  int hk = (blk >> 5) & 3;
  int b = blk >> 7;
  int s0 = st * 64;
#pragma unroll
  for (int i = 0; i < 16; i++) {
    int ii = threadIdx.x + i*256;
    int r = ii >> 6, cc = ii & 63;
    tile[r][cc] = qkv[((size_t)(b*S_) + s0 + r)*QKVN + (NQ_+NKV_)*64 + hk*64 + cc];
  }
  __syncthreads();
#pragma unroll
  for (int i = 0; i < 16; i++) {
    int ii = threadIdx.x + i*256;
    int d = ii >> 6, s = ii & 63;
    vt[((size_t)(b*NKV_ + hk)*64 + d)*S_ + s0 + s] = tile[s][d];
  }
}

// ---------------- Flash attention, one wave per (b,h,32-query tile) ----------------
// R5 counters: 71 us, Occupancy 8.6%, VALU 20.6% -> latency-bound at 6 waves/CU.
// This round: 32-query tiles (3072 waves = 12/CU), wave-uniform full-tile fast
// path (3 of 5 key tiles unmasked), unsigned-range mask, exp-underflow instead of
// select, packed u64 epilogue.
__global__ __launch_bounds__(64, 4) void k_attn(const u16* __restrict__ q,
                                                const u16* __restrict__ k,
                                                const u16* __restrict__ vt,
                                                u16* __restrict__ ao,
                                                const int* __restrict__ spp) {
  __shared__ __align__(16) u16 Pt[32*72];
  int blk = blockIdx.x;
  int qb = blk & 63;
  int rest = blk >> 6;
  int h = rest % NQ_;
  int b = rest / NQ_;
  int q0 = qb * 32;
  int hk = h / (NQ_/NKV_);
  int l = threadIdx.x;
  int c = l & 15, g = l >> 4;
  int sp = spp[0];
  const u16* qptr = q + ((size_t)(b*NQ_ + h))*S_*64;
  const u16* kptr = k + ((size_t)(b*NKV_ + hk))*S_*64;
  const u16* vptr = vt + ((size_t)(b*NKV_ + hk))*64*S_;

  s16x8 qf[2][2];
#pragma unroll
  for (int qt = 0; qt < 2; qt++)
#pragma unroll
    for (int ks = 0; ks < 2; ks++)
      qf[qt][ks] = *(const s16x8*)(qptr + (size_t)(q0 + qt*16 + c)*64 + ks*32 + g*8);

  f32x4 o[4][2] = {};          // o[dt][qt]: O^T accum, row=d col=q
  float m_run[2], l_run[2];
#pragma unroll
  for (int i = 0; i < 2; i++) { m_run[i] = -1e30f; l_run[i] = 0.f; }

  int lo = sp + q0 - 256; if (lo < 0) lo = 0;
  int hi = sp + q0 + 31;  if (hi > S_ - 1) hi = S_ - 1;
  for (int kt = (lo >> 6); kt <= (hi >> 6); kt++) {
    s16x8 kf[4][2];
#pragma unroll
    for (int km = 0; km < 4; km++)
#pragma unroll
      for (int ks = 0; ks < 2; ks++)
        kf[km][ks] = *(const s16x8*)(kptr + (size_t)(kt*64 + km*16 + c)*64 + ks*32 + g*8);
    f32x4 sa[4][2];            // sa[km][qt]: S^T tile, row=key col=query
#pragma unroll
    for (int km = 0; km < 4; km++)
#pragma unroll
      for (int qt = 0; qt < 2; qt++) {
        f32x4 z = {};
        z = __builtin_amdgcn_mfma_f32_16x16x32_bf16(kf[km][0], qf[qt][0], z, 0, 0, 0);
        sa[km][qt] = __builtin_amdgcn_mfma_f32_16x16x32_bf16(kf[km][1], qf[qt][1], z, 0, 0, 0);
      }
    // fully-valid tile for the whole wave? (wave-uniform branch)
    bool full = (kt*64 + 63 <= sp + q0) && (kt*64 >= sp + q0 - 225);
    // Fence: previous iteration's Pt reads must complete before overwrite.
    __syncthreads();
#pragma unroll
    for (int qt = 0; qt < 2; qt++) {
      float mx = -1e30f;
      if (full) {
#pragma unroll
        for (int km = 0; km < 4; km++)
#pragma unroll
          for (int r = 0; r < 4; r++) {
            float sv = sa[km][qt][r] * 0.125f;
            sa[km][qt][r] = sv;
            mx = fmaxf(mx, sv);
          }
      } else {
        int pos = sp + q0 + qt*16 + c;
#pragma unroll
        for (int km = 0; km < 4; km++)
#pragma unroll
          for (int r = 0; r < 4; r++) {
            int key = kt*64 + km*16 + g*4 + r;
            float sv = sa[km][qt][r] * 0.125f;
            sv = ((unsigned)(pos - key) <= 256u) ? sv : -1e30f;
            sa[km][qt][r] = sv;
            mx = fmaxf(mx, sv);
          }
      }
      mx = fmaxf(mx, __shfl_xor(mx, 16));
      mx = fmaxf(mx, __shfl_xor(mx, 32));
      float mnew = fmaxf(m_run[qt], mx);
      float alpha = __expf(m_run[qt] - mnew);
      m_run[qt] = mnew;
      float rsum = 0.f;
#pragma unroll
      for (int km = 0; km < 4; km++) {
        float p0 = __expf(sa[km][qt][0] - mnew);   // masked -1e30 underflows to 0
        float p1 = __expf(sa[km][qt][1] - mnew);
        float p2 = __expf(sa[km][qt][2] - mnew);
        float p3 = __expf(sa[km][qt][3] - mnew);
        rsum += p0 + p1 + p2 + p3;
        *(unsigned long long*)(Pt + (qt*16 + c)*72 + km*16 + g*4) = pk4bf(p0, p1, p2, p3);
      }
      rsum += __shfl_xor(rsum, 16);
      rsum += __shfl_xor(rsum, 32);
      l_run[qt] = l_run[qt]*alpha + rsum;
#pragma unroll
      for (int dt = 0; dt < 4; dt++) {
        o[dt][qt][0] *= alpha; o[dt][qt][1] *= alpha;
        o[dt][qt][2] *= alpha; o[dt][qt][3] *= alpha;
      }
    }
    // Fence: Pt writes visible before the typed-differently reads below.
    __syncthreads();
    // PV: O^T += V^T @ P^T
#pragma unroll
    for (int ks = 0; ks < 2; ks++) {
      s16x8 vf[4];
#pragma unroll
      for (int dt = 0; dt < 4; dt++)
        vf[dt] = *(const s16x8*)(vptr + (size_t)(dt*16 + c)*S_ + kt*64 + ks*32 + g*8);
#pragma unroll
      for (int qt = 0; qt < 2; qt++) {
        s16x8 pf = *(const s16x8*)(Pt + (qt*16 + c)*72 + ks*32 + g*8);
#pragma unroll
        for (int dt = 0; dt < 4; dt++)
          o[dt][qt] = __builtin_amdgcn_mfma_f32_16x16x32_bf16(vf[dt], pf, o[dt][qt], 0, 0, 0);
      }
    }
  }
#pragma unroll
  for (int qt = 0; qt < 2; qt++) {
    float inv = 1.f / l_run[qt];
    int qi = q0 + qt*16 + c;
    u16* row = ao + ((size_t)(b*S_) + qi)*HID + h*64;
#pragma unroll
    for (int dt = 0; dt < 4; dt++)
      *(unsigned long long*)(row + dt*16 + g*4) =
          pk4bf(o[dt][qt][0]*inv, o[dt][qt][1]*inv, o[dt][qt][2]*inv, o[dt][qt][3]*inv);
  }
}

extern "C" void kernel_launch(void* const* d_in, const int* in_sizes, int n_in,
                              void* d_out, int out_size, void* d_ws, size_t ws_size,
                              hipStream_t stream) {
  const float* x_f32    = (const float*)d_in[0];
  const float* g_f32    = (const float*)d_in[1];
  const float* wqkv_f32 = (const float*)d_in[2];
  const float* wout_f32 = (const float*)d_in[3];
  const int*   spp      = (const int*)d_in[4];
  char* ws = (char*)d_ws;
  // workspace layout (bytes), ~57.1 MB total
  u16* wqkvb = (u16*)(ws);                    //  6,291,456
  u16* woutb = (u16*)(ws + 6291456);          //  4,718,592
  u16* xn    = (u16*)(ws + 11010048);         // 12,582,912
  u16* qkv   = (u16*)(ws + 23592960);         // 16,777,216
  u16* qbuf  = (u16*)(ws + 40370176);         // 12,582,912
  u16* kbuf  = (u16*)(ws + 52953088);         //  2,097,152
  u16* vtb   = (u16*)(ws + 55050240);         //  2,097,152  (end 57,147,392)
  u16* attn  = xn;                            // aliases xn (dead after GEMM1)

  const int nwq = QKVN*HID, nwo = HID*HID;
  k_cvt<<<(nwq/4 + 255)/256, 256, 0, stream>>>(wqkv_f32, wqkvb, nwq/4);
  k_cvt<<<(nwo/4 + 255)/256, 256, 0, stream>>>(wout_f32, woutb, nwo/4);

  k_rmsnorm<<<NTOK, 384, 0, stream>>>(x_f32, g_f32, xn);
  k_gemm_bt<false><<<dim3(QKVN/128, NTOK/128), 256, 0, stream>>>(xn, wqkvb, qkv, nullptr, NTOK, QKVN, HID);
  k_rope<<<(NTOK*28*32)/256, 256, 0, stream>>>(qkv, qbuf, kbuf, spp);
  k_vt<<<B_*NKV_*(S_/64), 256, 0, stream>>>(qkv, vtb);
  k_attn<<<B_*NQ_*(S_/32), 64, 0, stream>>>(qbuf, kbuf, vtb, attn, spp);
  k_gemm_bt<true><<<dim3(HID/128, NTOK/128), 256, 0, stream>>>(attn, woutb, d_out, x_f32, NTOK, HID, HID);
}

// Round 7
// 252.625 us; speedup vs baseline: 1.0296x; 1.0198x over previous
//
#include <hip/hip_runtime.h>
#include <hip/hip_bf16.h>

typedef float f32x4 __attribute__((ext_vector_type(4)));
typedef short s16x8 __attribute__((ext_vector_type(8)));
typedef unsigned short u16;

#define B_ 2
#define S_ 2048
#define HID 1536
#define NQ_ 24
#define NKV_ 4
#define HD 64
#define NTOK (B_*S_)
#define QKVN ((NQ_+2*NKV_)*HD)   // 2048

// Compiler-only memory fence. Within a single wave the LDS pipe executes DS ops
// in issue order, so write->read ordering needs no s_barrier (which would force
// a vmcnt(0) drain of all in-flight global loads -- the R6 53us stall).
#define LDS_FENCE() asm volatile("" ::: "memory")

__device__ __forceinline__ float bf2f(u16 u) {
  unsigned int x = ((unsigned int)u) << 16;
  float f; __builtin_memcpy(&f, &x, 4); return f;
}
__device__ __forceinline__ u16 f2bf(float f) {
  unsigned int u; __builtin_memcpy(&u, &f, 4);
  u += 0x7fffu + ((u >> 16) & 1u);
  return (u16)(u >> 16);
}
// 4x f32 -> packed bf16x4 via v_cvt_pk_bf16_f32 (2 instrs vs ~19 scalar ops)
__device__ __forceinline__ unsigned long long pk4bf(float a, float b, float c, float d) {
  __hip_bfloat162 x = __float22bfloat162_rn(make_float2(a, b));
  __hip_bfloat162 y = __float22bfloat162_rn(make_float2(c, d));
  unsigned int xi, yi;
  __builtin_memcpy(&xi, &x, 4);
  __builtin_memcpy(&yi, &y, 4);
  return (unsigned long long)xi | ((unsigned long long)yi << 32);
}

// ---------------- fp32 -> bf16 weight conversion ----------------
__global__ __launch_bounds__(256) void k_cvt(const float* __restrict__ src,
                                             u16* __restrict__ dst, int n4) {
  int i = blockIdx.x * 256 + threadIdx.x;   // units of 4 elements
  if (i >= n4) return;
  f32x4 v = ((const f32x4*)src)[i];
  *(unsigned long long*)(dst + (size_t)i*4) = pk4bf(v[0], v[1], v[2], v[3]);
}

// ---------------- RMSNorm (fused fp32 read -> bf16 write) ----------------
__global__ __launch_bounds__(384) void k_rmsnorm(const float* __restrict__ x,
                                                 const float* __restrict__ g,
                                                 u16* __restrict__ xn) {
  int row = blockIdx.x;
  int t = threadIdx.x;
  f32x4 v = ((const f32x4*)(x + (size_t)row * HID))[t];
  float ss = v[0]*v[0] + v[1]*v[1] + v[2]*v[2] + v[3]*v[3];
#pragma unroll
  for (int off = 1; off < 64; off <<= 1) ss += __shfl_xor(ss, off);
  __shared__ float red[6];
  if ((t & 63) == 0) red[t >> 6] = ss;
  __syncthreads();
  float tot = red[0] + red[1] + red[2] + red[3] + red[4] + red[5];
  float rs = rsqrtf(tot * (1.f/HID) + 1e-6f);
  f32x4 gv = ((const f32x4*)g)[t];
  ((unsigned long long*)(xn + (size_t)row * HID))[t] =
      pk4bf(v[0]*rs*gv[0], v[1]*rs*gv[1], v[2]*rs*gv[2], v[3]*rs*gv[3]);
}

// ---------------- GEMM C[M][N] = A[M][K] @ W[N][K]^T ----------------
// m97-recipe. F32OUT: fp32 output + fp32 residual (final proj); else bf16 out.
template <bool F32OUT>
__global__ __launch_bounds__(256) void k_gemm_bt(const u16* __restrict__ A,
                                                 const u16* __restrict__ W,
                                                 void* __restrict__ Cv,
                                                 const float* __restrict__ resid,
                                                 int M, int N, int K) {
  __shared__ __align__(16) u16 As[128*32];
  __shared__ __align__(16) u16 Bs[128*32];
  int m0 = blockIdx.y * 128, n0 = blockIdx.x * 128;
  int tid = threadIdx.x;
  int w = tid >> 6, l = tid & 63;
  int wr = w >> 1, wc = w & 1;
  int c = l & 15, g = l >> 4;
  f32x4 acc[4][4] = {};
  const u16* Ag = A + (size_t)(m0 + w*32 + (l>>2))*K + (l&3)*8;
  const u16* Wg = W + (size_t)(n0 + w*32 + (l>>2))*K + (l&3)*8;
  u16* AsW = As + w*32*32;
  u16* BsW = Bs + w*32*32;
  for (int k0 = 0; k0 < K; k0 += 32) {
    __builtin_amdgcn_global_load_lds((const __attribute__((address_space(1))) void*)(Ag + k0),
                                     (__attribute__((address_space(3))) void*)AsW, 16, 0, 0);
    __builtin_amdgcn_global_load_lds((const __attribute__((address_space(1))) void*)(Ag + k0 + (size_t)16*K),
                                     (__attribute__((address_space(3))) void*)(AsW + 16*32), 16, 0, 0);
    __builtin_amdgcn_global_load_lds((const __attribute__((address_space(1))) void*)(Wg + k0),
                                     (__attribute__((address_space(3))) void*)BsW, 16, 0, 0);
    __builtin_amdgcn_global_load_lds((const __attribute__((address_space(1))) void*)(Wg + k0 + (size_t)16*K),
                                     (__attribute__((address_space(3))) void*)(BsW + 16*32), 16, 0, 0);
    __syncthreads();
    s16x8 af[4], bq[4];
#pragma unroll
    for (int mt = 0; mt < 4; mt++) af[mt] = *(const s16x8*)(As + (wr*64 + mt*16 + c)*32 + g*8);
#pragma unroll
    for (int nt = 0; nt < 4; nt++) bq[nt] = *(const s16x8*)(Bs + (wc*64 + nt*16 + c)*32 + g*8);
#pragma unroll
    for (int mt = 0; mt < 4; mt++)
#pragma unroll
      for (int nt = 0; nt < 4; nt++)
        acc[mt][nt] = __builtin_amdgcn_mfma_f32_16x16x32_bf16(af[mt], bq[nt], acc[mt][nt], 0, 0, 0);
    __syncthreads();
  }
#pragma unroll
  for (int mt = 0; mt < 4; mt++)
#pragma unroll
    for (int nt = 0; nt < 4; nt++)
#pragma unroll
      for (int r = 0; r < 4; r++) {
        int m = m0 + wr*64 + mt*16 + g*4 + r;
        int n = n0 + wc*64 + nt*16 + c;
        size_t off = (size_t)m*N + n;
        float vv = acc[mt][nt][r];
        if (F32OUT) {
          ((float*)Cv)[off] = vv + resid[off];
        } else {
          ((u16*)Cv)[off] = f2bf(vv);
        }
      }
}

// ---------------- RoPE + scatter q,k ----------------
__global__ __launch_bounds__(256) void k_rope(const u16* __restrict__ qkv,
                                              u16* __restrict__ q,
                                              u16* __restrict__ k,
                                              const int* __restrict__ spp) {
  int idx = blockIdx.x * 256 + threadIdx.x;     // (tok*28 + h)*32 + p
  int p = idx & 31;
  int h = (idx >> 5) % 28;
  int tok = idx / 896;
  int s = tok & (S_ - 1);
  int b = tok >> 11;
  float t = (float)(spp[0] + s);
  float inv = powf(10000.f, -(float)p * (1.f/32.f));
  float fr = t * inv;
  float sn, cs;
  sincosf(fr, &sn, &cs);
  int col = (h < NQ_) ? h*64 + 2*p : HID + (h - NQ_)*64 + 2*p;
  unsigned int pr = *(const unsigned int*)(qkv + (size_t)tok*QKVN + col);
  float x1 = bf2f((u16)(pr & 0xffff));
  float x2 = bf2f((u16)(pr >> 16));
  float y1 = x1*cs - x2*sn;
  float y2 = x2*cs + x1*sn;
  unsigned int outp = (unsigned int)f2bf(y1) | ((unsigned int)f2bf(y2) << 16);
  if (h < NQ_) {
    *(unsigned int*)(q + (((size_t)(b*NQ_ + h))*S_ + s)*64 + 2*p) = outp;
  } else {
    *(unsigned int*)(k + (((size_t)(b*NKV_ + (h - NQ_)))*S_ + s)*64 + 2*p) = outp;
  }
}

// ---------------- V transpose: vt[b][hk][d][s] ----------------
__global__ __launch_bounds__(256) void k_vt(const u16* __restrict__ qkv,
                                            u16* __restrict__ vt) {
  __shared__ u16 tile[64][65];
  int blk = blockIdx.x;
  int st = blk & 31;
  int hk = (blk >> 5) & 3;
  int b = blk >> 7;
  int s0 = st * 64;
#pragma unroll
  for (int i = 0; i < 16; i++) {
    int ii = threadIdx.x + i*256;
    int r = ii >> 6, cc = ii & 63;
    tile[r][cc] = qkv[((size_t)(b*S_) + s0 + r)*QKVN + (NQ_+NKV_)*64 + hk*64 + cc];
  }
  __syncthreads();
#pragma unroll
  for (int i = 0; i < 16; i++) {
    int ii = threadIdx.x + i*256;
    int d = ii >> 6, s = ii & 63;
    vt[((size_t)(b*NKV_ + hk)*64 + d)*S_ + s0 + s] = tile[s][d];
  }
}

// ---------------- Flash attention, one wave per (b,h,32-query tile) ----------------
// R6: 53us @ VALUBusy 18% -> exposed-latency bound; culprit = __syncthreads
// forcing vmcnt(0) drains (compiler emits full waitcnt before s_barrier).
// R7: barriers -> compiler-only fences (single-wave block, DS pipe is in-order);
// V-tile loaded behind softmax; next K-tile prefetched behind PV; cvt_pk packing.
__global__ __launch_bounds__(64, 3) void k_attn(const u16* __restrict__ q,
                                                const u16* __restrict__ k,
                                                const u16* __restrict__ vt,
                                                u16* __restrict__ ao,
                                                const int* __restrict__ spp) {
  __shared__ __align__(16) u16 Pt[32*72];
  int blk = blockIdx.x;
  int qb = blk & 63;
  int rest = blk >> 6;
  int h = rest % NQ_;
  int b = rest / NQ_;
  int q0 = qb * 32;
  int hk = h / (NQ_/NKV_);
  int l = threadIdx.x;
  int c = l & 15, g = l >> 4;
  int sp = spp[0];
  const u16* qptr = q + ((size_t)(b*NQ_ + h))*S_*64;
  const u16* kptr = k + ((size_t)(b*NKV_ + hk))*S_*64;
  const u16* vptr = vt + ((size_t)(b*NKV_ + hk))*64*S_;

  s16x8 qf[2][2];
#pragma unroll
  for (int qt = 0; qt < 2; qt++)
#pragma unroll
    for (int ks = 0; ks < 2; ks++)
      qf[qt][ks] = *(const s16x8*)(qptr + (size_t)(q0 + qt*16 + c)*64 + ks*32 + g*8);

  f32x4 o[4][2] = {};          // o[dt][qt]: O^T accum, row=d col=q
  float m_run[2], l_run[2];
#pragma unroll
  for (int i = 0; i < 2; i++) { m_run[i] = -1e30f; l_run[i] = 0.f; }

  int lo = sp + q0 - 256; if (lo < 0) lo = 0;
  int hi = sp + q0 + 31;  if (hi > S_ - 1) hi = S_ - 1;
  int kt0 = lo >> 6, kt1 = hi >> 6;

  s16x8 kf[4][2];
#pragma unroll
  for (int km = 0; km < 4; km++)
#pragma unroll
    for (int ks = 0; ks < 2; ks++)
      kf[km][ks] = *(const s16x8*)(kptr + (size_t)(kt0*64 + km*16 + c)*64 + ks*32 + g*8);

  for (int kt = kt0; kt <= kt1; kt++) {
    f32x4 sa[4][2];            // sa[km][qt]: S^T tile, row=key col=query
#pragma unroll
    for (int km = 0; km < 4; km++)
#pragma unroll
      for (int qt = 0; qt < 2; qt++) {
        f32x4 z = {};
        z = __builtin_amdgcn_mfma_f32_16x16x32_bf16(kf[km][0], qf[qt][0], z, 0, 0, 0);
        sa[km][qt] = __builtin_amdgcn_mfma_f32_16x16x32_bf16(kf[km][1], qf[qt][1], z, 0, 0, 0);
      }
    // V-tile loads issued now: latency hides behind the softmax VALU below.
    s16x8 vf[2][4];
#pragma unroll
    for (int ks = 0; ks < 2; ks++)
#pragma unroll
      for (int dt = 0; dt < 4; dt++)
        vf[ks][dt] = *(const s16x8*)(vptr + (size_t)(dt*16 + c)*S_ + kt*64 + ks*32 + g*8);

    bool full = (kt*64 + 63 <= sp + q0) && (kt*64 >= sp + q0 - 225);
#pragma unroll
    for (int qt = 0; qt < 2; qt++) {
      float mx = -1e30f;
      if (full) {
#pragma unroll
        for (int km = 0; km < 4; km++)
#pragma unroll
          for (int r = 0; r < 4; r++) {
            float sv = sa[km][qt][r] * 0.125f;
            sa[km][qt][r] = sv;
            mx = fmaxf(mx, sv);
          }
      } else {
        int pos = sp + q0 + qt*16 + c;
#pragma unroll
        for (int km = 0; km < 4; km++)
#pragma unroll
          for (int r = 0; r < 4; r++) {
            int key = kt*64 + km*16 + g*4 + r;
            float sv = sa[km][qt][r] * 0.125f;
            sv = ((unsigned)(pos - key) <= 256u) ? sv : -1e30f;
            sa[km][qt][r] = sv;
            mx = fmaxf(mx, sv);
          }
      }
      mx = fmaxf(mx, __shfl_xor(mx, 16));
      mx = fmaxf(mx, __shfl_xor(mx, 32));
      float mnew = fmaxf(m_run[qt], mx);
      float alpha = __expf(m_run[qt] - mnew);
      m_run[qt] = mnew;
      float rsum = 0.f;
#pragma unroll
      for (int km = 0; km < 4; km++) {
        float p0 = __expf(sa[km][qt][0] - mnew);   // masked -1e30 underflows to 0
        float p1 = __expf(sa[km][qt][1] - mnew);
        float p2 = __expf(sa[km][qt][2] - mnew);
        float p3 = __expf(sa[km][qt][3] - mnew);
        rsum += p0 + p1 + p2 + p3;
        *(unsigned long long*)(Pt + (qt*16 + c)*72 + km*16 + g*4) = pk4bf(p0, p1, p2, p3);
      }
      rsum += __shfl_xor(rsum, 16);
      rsum += __shfl_xor(rsum, 32);
      l_run[qt] = l_run[qt]*alpha + rsum;
#pragma unroll
      for (int dt = 0; dt < 4; dt++) {
        o[dt][qt][0] *= alpha; o[dt][qt][1] *= alpha;
        o[dt][qt][2] *= alpha; o[dt][qt][3] *= alpha;
      }
    }
    // Prefetch next K-tile: latency hides behind the PV MFMAs.
    if (kt < kt1) {
#pragma unroll
      for (int km = 0; km < 4; km++)
#pragma unroll
        for (int ks = 0; ks < 2; ks++)
          kf[km][ks] = *(const s16x8*)(kptr + (size_t)((kt+1)*64 + km*16 + c)*64 + ks*32 + g*8);
    }
    LDS_FENCE();   // Pt writes ordered before reads (in-order DS pipe, same wave)
    // PV: O^T += V^T @ P^T
#pragma unroll
    for (int ks = 0; ks < 2; ks++)
#pragma unroll
      for (int qt = 0; qt < 2; qt++) {
        s16x8 pf = *(const s16x8*)(Pt + (qt*16 + c)*72 + ks*32 + g*8);
#pragma unroll
        for (int dt = 0; dt < 4; dt++)
          o[dt][qt] = __builtin_amdgcn_mfma_f32_16x16x32_bf16(vf[ks][dt], pf, o[dt][qt], 0, 0, 0);
      }
    LDS_FENCE();   // Pt reads ordered before next iteration's writes
  }
#pragma unroll
  for (int qt = 0; qt < 2; qt++) {
    float inv = 1.f / l_run[qt];
    int qi = q0 + qt*16 + c;
    u16* row = ao + ((size_t)(b*S_) + qi)*HID + h*64;
#pragma unroll
    for (int dt = 0; dt < 4; dt++)
      *(unsigned long long*)(row + dt*16 + g*4) =
          pk4bf(o[dt][qt][0]*inv, o[dt][qt][1]*inv, o[dt][qt][2]*inv, o[dt][qt][3]*inv);
  }
}

extern "C" void kernel_launch(void* const* d_in, const int* in_sizes, int n_in,
                              void* d_out, int out_size, void* d_ws, size_t ws_size,
                              hipStream_t stream) {
  const float* x_f32    = (const float*)d_in[0];
  const float* g_f32    = (const float*)d_in[1];
  const float* wqkv_f32 = (const float*)d_in[2];
  const float* wout_f32 = (const float*)d_in[3];
  const int*   spp      = (const int*)d_in[4];
  char* ws = (char*)d_ws;
  // workspace layout (bytes), ~57.1 MB total
  u16* wqkvb = (u16*)(ws);                    //  6,291,456
  u16* woutb = (u16*)(ws + 6291456);          //  4,718,592
  u16* xn    = (u16*)(ws + 11010048);         // 12,582,912
  u16* qkv   = (u16*)(ws + 23592960);         // 16,777,216
  u16* qbuf  = (u16*)(ws + 40370176);         // 12,582,912
  u16* kbuf  = (u16*)(ws + 52953088);         //  2,097,152
  u16* vtb   = (u16*)(ws + 55050240);         //  2,097,152  (end 57,147,392)
  u16* attn  = xn;                            // aliases xn (dead after GEMM1)

  const int nwq = QKVN*HID, nwo = HID*HID;
  k_cvt<<<(nwq/4 + 255)/256, 256, 0, stream>>>(wqkv_f32, wqkvb, nwq/4);
  k_cvt<<<(nwo/4 + 255)/256, 256, 0, stream>>>(wout_f32, woutb, nwo/4);

  k_rmsnorm<<<NTOK, 384, 0, stream>>>(x_f32, g_f32, xn);
  k_gemm_bt<false><<<dim3(QKVN/128, NTOK/128), 256, 0, stream>>>(xn, wqkvb, qkv, nullptr, NTOK, QKVN, HID);
  k_rope<<<(NTOK*28*32)/256, 256, 0, stream>>>(qkv, qbuf, kbuf, spp);
  k_vt<<<B_*NKV_*(S_/64), 256, 0, stream>>>(qkv, vtb);
  k_attn<<<B_*NQ_*(S_/32), 64, 0, stream>>>(qbuf, kbuf, vtb, attn, spp);
  k_gemm_bt<true><<<dim3(HID/128, NTOK/128), 256, 0, stream>>>(attn, woutb, d_out, x_f32, NTOK, HID, HID);
}

// Round 8
// 234.098 us; speedup vs baseline: 1.1111x; 1.0791x over previous
//
#include <hip/hip_runtime.h>
#include <hip/hip_bf16.h>

typedef float f32x4 __attribute__((ext_vector_type(4)));
typedef short s16x8 __attribute__((ext_vector_type(8)));
typedef unsigned short u16;

#define B_ 2
#define S_ 2048
#define HID 1536
#define NQ_ 24
#define NKV_ 4
#define HD 64
#define NTOK (B_*S_)
#define QKVN ((NQ_+2*NKV_)*HD)   // 2048
#define ROPE_BLOCKS ((NTOK*28*32)/256)   // 14336
#define VT_BLOCKS (B_*NKV_*(S_/64))      // 256

// Compiler-only memory fence (single-wave block: LDS pipe is in-order, no s_barrier
// needed -> avoids the vmcnt(0) drain). Proven R6->R7 on k_attn.
#define LDS_FENCE() asm volatile("" ::: "memory")

__device__ __forceinline__ float bf2f(u16 u) {
  unsigned int x = ((unsigned int)u) << 16;
  float f; __builtin_memcpy(&f, &x, 4); return f;
}
__device__ __forceinline__ u16 f2bf(float f) {
  unsigned int u; __builtin_memcpy(&u, &f, 4);
  u += 0x7fffu + ((u >> 16) & 1u);
  return (u16)(u >> 16);
}
// 4x f32 -> packed bf16x4 via v_cvt_pk_bf16_f32
__device__ __forceinline__ unsigned long long pk4bf(float a, float b, float c, float d) {
  __hip_bfloat162 x = __float22bfloat162_rn(make_float2(a, b));
  __hip_bfloat162 y = __float22bfloat162_rn(make_float2(c, d));
  unsigned int xi, yi;
  __builtin_memcpy(&xi, &x, 4);
  __builtin_memcpy(&yi, &y, 4);
  return (unsigned long long)xi | ((unsigned long long)yi << 32);
}

// ---------------- fused fp32 -> bf16 conversion of both weight matrices ----------------
// Destinations are adjacent in ws, so one grid covers both (saves a launch).
__global__ __launch_bounds__(256) void k_cvt2(const float* __restrict__ s0, int n0q,
                                              const float* __restrict__ s1, int n1q,
                                              u16* __restrict__ dst) {
  int i = blockIdx.x * 256 + threadIdx.x;   // units of 4 elements
  if (i >= n0q + n1q) return;
  const float* src = (i < n0q) ? s0 : s1;
  int j = (i < n0q) ? i : i - n0q;
  f32x4 v = ((const f32x4*)src)[j];
  *(unsigned long long*)(dst + (size_t)i*4) = pk4bf(v[0], v[1], v[2], v[3]);
}

// ---------------- RMSNorm (fused fp32 read -> bf16 write) ----------------
__global__ __launch_bounds__(384) void k_rmsnorm(const float* __restrict__ x,
                                                 const float* __restrict__ g,
                                                 u16* __restrict__ xn) {
  int row = blockIdx.x;
  int t = threadIdx.x;
  f32x4 v = ((const f32x4*)(x + (size_t)row * HID))[t];
  float ss = v[0]*v[0] + v[1]*v[1] + v[2]*v[2] + v[3]*v[3];
#pragma unroll
  for (int off = 1; off < 64; off <<= 1) ss += __shfl_xor(ss, off);
  __shared__ float red[6];
  if ((t & 63) == 0) red[t >> 6] = ss;
  __syncthreads();
  float tot = red[0] + red[1] + red[2] + red[3] + red[4] + red[5];
  float rs = rsqrtf(tot * (1.f/HID) + 1e-6f);
  f32x4 gv = ((const f32x4*)g)[t];
  ((unsigned long long*)(xn + (size_t)row * HID))[t] =
      pk4bf(v[0]*rs*gv[0], v[1]*rs*gv[1], v[2]*rs*gv[2], v[3]*rs*gv[3]);
}

// ---------------- GEMM C[M][N] = A[M][K] @ W[N][K]^T, M fixed = 4096 ----------------
// R7 counters: 49us, MfmaUtil 14%, FETCH 66MB (ideal 19) -> barrier-drain at small K
// + cross-XCD A re-fetch. R8: (a) K unrolled x2 with two LDS buffer pairs -> 32 MFMAs
// per barrier pair (AITER density), half the vmcnt(0) drains; (b) XCD-aware swizzle:
// lin&7 = XCD owns a contiguous 4-Mtile stripe (A-stripe 1.6MB resident in its 4MB L2),
// m-inner traversal reuses each W-tile 4x.
template <bool F32OUT>
__global__ __launch_bounds__(256) void k_gemm_bt(const u16* __restrict__ A,
                                                 const u16* __restrict__ W,
                                                 void* __restrict__ Cv,
                                                 const float* __restrict__ resid,
                                                 int N, int K) {
  __shared__ __align__(16) u16 As[2][128*32];
  __shared__ __align__(16) u16 Bs[2][128*32];
  int lin = blockIdx.x;
  int xcd = lin & 7, loc = lin >> 3;
  int mloc = loc & 3, nloc = loc >> 2;          // stripe height 4 (32 Mtiles / 8 XCDs)
  int m0 = (xcd*4 + mloc) * 128, n0 = nloc * 128;
  int tid = threadIdx.x;
  int w = tid >> 6, l = tid & 63;
  int wr = w >> 1, wc = w & 1;
  int c = l & 15, g = l >> 4;
  f32x4 acc[4][4] = {};
  const u16* Ag = A + (size_t)(m0 + w*32 + (l>>2))*K + (l&3)*8;
  const u16* Wg = W + (size_t)(n0 + w*32 + (l>>2))*K + (l&3)*8;
  const int woff = w*32*32;
  for (int k0 = 0; k0 < K; k0 += 64) {
#pragma unroll
    for (int hf = 0; hf < 2; hf++) {
      int kk = k0 + hf*32;
      __builtin_amdgcn_global_load_lds((const __attribute__((address_space(1))) void*)(Ag + kk),
                                       (__attribute__((address_space(3))) void*)(As[hf] + woff), 16, 0, 0);
      __builtin_amdgcn_global_load_lds((const __attribute__((address_space(1))) void*)(Ag + kk + (size_t)16*K),
                                       (__attribute__((address_space(3))) void*)(As[hf] + woff + 16*32), 16, 0, 0);
      __builtin_amdgcn_global_load_lds((const __attribute__((address_space(1))) void*)(Wg + kk),
                                       (__attribute__((address_space(3))) void*)(Bs[hf] + woff), 16, 0, 0);
      __builtin_amdgcn_global_load_lds((const __attribute__((address_space(1))) void*)(Wg + kk + (size_t)16*K),
                                       (__attribute__((address_space(3))) void*)(Bs[hf] + woff + 16*32), 16, 0, 0);
    }
    __syncthreads();
#pragma unroll
    for (int hf = 0; hf < 2; hf++) {
      s16x8 af[4], bq[4];
#pragma unroll
      for (int mt = 0; mt < 4; mt++) af[mt] = *(const s16x8*)(As[hf] + (wr*64 + mt*16 + c)*32 + g*8);
#pragma unroll
      for (int nt = 0; nt < 4; nt++) bq[nt] = *(const s16x8*)(Bs[hf] + (wc*64 + nt*16 + c)*32 + g*8);
#pragma unroll
      for (int mt = 0; mt < 4; mt++)
#pragma unroll
        for (int nt = 0; nt < 4; nt++)
          acc[mt][nt] = __builtin_amdgcn_mfma_f32_16x16x32_bf16(af[mt], bq[nt], acc[mt][nt], 0, 0, 0);
    }
    __syncthreads();
  }
#pragma unroll
  for (int mt = 0; mt < 4; mt++)
#pragma unroll
    for (int nt = 0; nt < 4; nt++)
#pragma unroll
      for (int r = 0; r < 4; r++) {
        int m = m0 + wr*64 + mt*16 + g*4 + r;
        int n = n0 + wc*64 + nt*16 + c;
        size_t off = (size_t)m*N + n;
        float vv = acc[mt][nt][r];
        if (F32OUT) {
          ((float*)Cv)[off] = vv + resid[off];
        } else {
          ((u16*)Cv)[off] = f2bf(vv);
        }
      }
}

// ---------------- fused RoPE(q,k) + V transpose (one launch) ----------------
__global__ __launch_bounds__(256) void k_rope_vt(const u16* __restrict__ qkv,
                                                 u16* __restrict__ q,
                                                 u16* __restrict__ k,
                                                 u16* __restrict__ vt,
                                                 const int* __restrict__ spp) {
  __shared__ u16 tile[64][65];
  int bid = blockIdx.x;
  if (bid < ROPE_BLOCKS) {
    int idx = bid * 256 + threadIdx.x;     // (tok*28 + h)*32 + p
    int p = idx & 31;
    int h = (idx >> 5) % 28;
    int tok = idx / 896;
    int s = tok & (S_ - 1);
    int b = tok >> 11;
    float t = (float)(spp[0] + s);
    float inv = powf(10000.f, -(float)p * (1.f/32.f));
    float fr = t * inv;
    float sn, cs;
    sincosf(fr, &sn, &cs);
    int col = (h < NQ_) ? h*64 + 2*p : HID + (h - NQ_)*64 + 2*p;
    unsigned int pr = *(const unsigned int*)(qkv + (size_t)tok*QKVN + col);
    float x1 = bf2f((u16)(pr & 0xffff));
    float x2 = bf2f((u16)(pr >> 16));
    float y1 = x1*cs - x2*sn;
    float y2 = x2*cs + x1*sn;
    unsigned int outp = (unsigned int)f2bf(y1) | ((unsigned int)f2bf(y2) << 16);
    if (h < NQ_) {
      *(unsigned int*)(q + (((size_t)(b*NQ_ + h))*S_ + s)*64 + 2*p) = outp;
    } else {
      *(unsigned int*)(k + (((size_t)(b*NKV_ + (h - NQ_)))*S_ + s)*64 + 2*p) = outp;
    }
  } else {
    int blk = bid - ROPE_BLOCKS;
    int st = blk & 31;
    int hk = (blk >> 5) & 3;
    int b = blk >> 7;
    int s0 = st * 64;
#pragma unroll
    for (int i = 0; i < 16; i++) {
      int ii = threadIdx.x + i*256;
      int r = ii >> 6, cc = ii & 63;
      tile[r][cc] = qkv[((size_t)(b*S_) + s0 + r)*QKVN + (NQ_+NKV_)*64 + hk*64 + cc];
    }
    __syncthreads();
#pragma unroll
    for (int i = 0; i < 16; i++) {
      int ii = threadIdx.x + i*256;
      int d = ii >> 6, s = ii & 63;
      vt[((size_t)(b*NKV_ + hk)*64 + d)*S_ + s0 + s] = tile[s][d];
    }
  }
}

// ---------------- Flash attention, one wave per (b,h,32-query tile) ----------------
// R7-verified: barrier-free (compiler fences only), V loads behind softmax,
// K-tile prefetch behind PV.
__global__ __launch_bounds__(64, 3) void k_attn(const u16* __restrict__ q,
                                                const u16* __restrict__ k,
                                                const u16* __restrict__ vt,
                                                u16* __restrict__ ao,
                                                const int* __restrict__ spp) {
  __shared__ __align__(16) u16 Pt[32*72];
  int blk = blockIdx.x;
  int qb = blk & 63;
  int rest = blk >> 6;
  int h = rest % NQ_;
  int b = rest / NQ_;
  int q0 = qb * 32;
  int hk = h / (NQ_/NKV_);
  int l = threadIdx.x;
  int c = l & 15, g = l >> 4;
  int sp = spp[0];
  const u16* qptr = q + ((size_t)(b*NQ_ + h))*S_*64;
  const u16* kptr = k + ((size_t)(b*NKV_ + hk))*S_*64;
  const u16* vptr = vt + ((size_t)(b*NKV_ + hk))*64*S_;

  s16x8 qf[2][2];
#pragma unroll
  for (int qt = 0; qt < 2; qt++)
#pragma unroll
    for (int ks = 0; ks < 2; ks++)
      qf[qt][ks] = *(const s16x8*)(qptr + (size_t)(q0 + qt*16 + c)*64 + ks*32 + g*8);

  f32x4 o[4][2] = {};          // o[dt][qt]: O^T accum, row=d col=q
  float m_run[2], l_run[2];
#pragma unroll
  for (int i = 0; i < 2; i++) { m_run[i] = -1e30f; l_run[i] = 0.f; }

  int lo = sp + q0 - 256; if (lo < 0) lo = 0;
  int hi = sp + q0 + 31;  if (hi > S_ - 1) hi = S_ - 1;
  int kt0 = lo >> 6, kt1 = hi >> 6;

  s16x8 kf[4][2];
#pragma unroll
  for (int km = 0; km < 4; km++)
#pragma unroll
    for (int ks = 0; ks < 2; ks++)
      kf[km][ks] = *(const s16x8*)(kptr + (size_t)(kt0*64 + km*16 + c)*64 + ks*32 + g*8);

  for (int kt = kt0; kt <= kt1; kt++) {
    f32x4 sa[4][2];            // sa[km][qt]: S^T tile, row=key col=query
#pragma unroll
    for (int km = 0; km < 4; km++)
#pragma unroll
      for (int qt = 0; qt < 2; qt++) {
        f32x4 z = {};
        z = __builtin_amdgcn_mfma_f32_16x16x32_bf16(kf[km][0], qf[qt][0], z, 0, 0, 0);
        sa[km][qt] = __builtin_amdgcn_mfma_f32_16x16x32_bf16(kf[km][1], qf[qt][1], z, 0, 0, 0);
      }
    // V-tile loads issued now: latency hides behind the softmax VALU below.
    s16x8 vf[2][4];
#pragma unroll
    for (int ks = 0; ks < 2; ks++)
#pragma unroll
      for (int dt = 0; dt < 4; dt++)
        vf[ks][dt] = *(const s16x8*)(vptr + (size_t)(dt*16 + c)*S_ + kt*64 + ks*32 + g*8);

    bool full = (kt*64 + 63 <= sp + q0) && (kt*64 >= sp + q0 - 225);
#pragma unroll
    for (int qt = 0; qt < 2; qt++) {
      float mx = -1e30f;
      if (full) {
#pragma unroll
        for (int km = 0; km < 4; km++)
#pragma unroll
          for (int r = 0; r < 4; r++) {
            float sv = sa[km][qt][r] * 0.125f;
            sa[km][qt][r] = sv;
            mx = fmaxf(mx, sv);
          }
      } else {
        int pos = sp + q0 + qt*16 + c;
#pragma unroll
        for (int km = 0; km < 4; km++)
#pragma unroll
          for (int r = 0; r < 4; r++) {
            int key = kt*64 + km*16 + g*4 + r;
            float sv = sa[km][qt][r] * 0.125f;
            sv = ((unsigned)(pos - key) <= 256u) ? sv : -1e30f;
            sa[km][qt][r] = sv;
            mx = fmaxf(mx, sv);
          }
      }
      mx = fmaxf(mx, __shfl_xor(mx, 16));
      mx = fmaxf(mx, __shfl_xor(mx, 32));
      float mnew = fmaxf(m_run[qt], mx);
      float alpha = __expf(m_run[qt] - mnew);
      m_run[qt] = mnew;
      float rsum = 0.f;
#pragma unroll
      for (int km = 0; km < 4; km++) {
        float p0 = __expf(sa[km][qt][0] - mnew);   // masked -1e30 underflows to 0
        float p1 = __expf(sa[km][qt][1] - mnew);
        float p2 = __expf(sa[km][qt][2] - mnew);
        float p3 = __expf(sa[km][qt][3] - mnew);
        rsum += p0 + p1 + p2 + p3;
        *(unsigned long long*)(Pt + (qt*16 + c)*72 + km*16 + g*4) = pk4bf(p0, p1, p2, p3);
      }
      rsum += __shfl_xor(rsum, 16);
      rsum += __shfl_xor(rsum, 32);
      l_run[qt] = l_run[qt]*alpha + rsum;
#pragma unroll
      for (int dt = 0; dt < 4; dt++) {
        o[dt][qt][0] *= alpha; o[dt][qt][1] *= alpha;
        o[dt][qt][2] *= alpha; o[dt][qt][3] *= alpha;
      }
    }
    // Prefetch next K-tile: latency hides behind the PV MFMAs.
    if (kt < kt1) {
#pragma unroll
      for (int km = 0; km < 4; km++)
#pragma unroll
        for (int ks = 0; ks < 2; ks++)
          kf[km][ks] = *(const s16x8*)(kptr + (size_t)((kt+1)*64 + km*16 + c)*64 + ks*32 + g*8);
    }
    LDS_FENCE();   // Pt writes ordered before reads (in-order DS pipe, same wave)
    // PV: O^T += V^T @ P^T
#pragma unroll
    for (int ks = 0; ks < 2; ks++)
#pragma unroll
      for (int qt = 0; qt < 2; qt++) {
        s16x8 pf = *(const s16x8*)(Pt + (qt*16 + c)*72 + ks*32 + g*8);
#pragma unroll
        for (int dt = 0; dt < 4; dt++)
          o[dt][qt] = __builtin_amdgcn_mfma_f32_16x16x32_bf16(vf[ks][dt], pf, o[dt][qt], 0, 0, 0);
      }
    LDS_FENCE();   // Pt reads ordered before next iteration's writes
  }
#pragma unroll
  for (int qt = 0; qt < 2; qt++) {
    float inv = 1.f / l_run[qt];
    int qi = q0 + qt*16 + c;
    u16* row = ao + ((size_t)(b*S_) + qi)*HID + h*64;
#pragma unroll
    for (int dt = 0; dt < 4; dt++)
      *(unsigned long long*)(row + dt*16 + g*4) =
          pk4bf(o[dt][qt][0]*inv, o[dt][qt][1]*inv, o[dt][qt][2]*inv, o[dt][qt][3]*inv);
  }
}

extern "C" void kernel_launch(void* const* d_in, const int* in_sizes, int n_in,
                              void* d_out, int out_size, void* d_ws, size_t ws_size,
                              hipStream_t stream) {
  const float* x_f32    = (const float*)d_in[0];
  const float* g_f32    = (const float*)d_in[1];
  const float* wqkv_f32 = (const float*)d_in[2];
  const float* wout_f32 = (const float*)d_in[3];
  const int*   spp      = (const int*)d_in[4];
  char* ws = (char*)d_ws;
  // workspace layout (bytes), ~57.1 MB total
  u16* wqkvb = (u16*)(ws);                    //  6,291,456
  u16* woutb = (u16*)(ws + 6291456);          //  4,718,592 (contiguous with wqkvb)
  u16* xn    = (u16*)(ws + 11010048);         // 12,582,912
  u16* qkv   = (u16*)(ws + 23592960);         // 16,777,216
  u16* qbuf  = (u16*)(ws + 40370176);         // 12,582,912
  u16* kbuf  = (u16*)(ws + 52953088);         //  2,097,152
  u16* vtb   = (u16*)(ws + 55050240);         //  2,097,152  (end 57,147,392)
  u16* attn  = xn;                            // aliases xn (dead after GEMM1)

  const int nwq4 = QKVN*HID/4, nwo4 = HID*HID/4;
  k_cvt2<<<(nwq4 + nwo4 + 255)/256, 256, 0, stream>>>(wqkv_f32, nwq4, wout_f32, nwo4, wqkvb);
  k_rmsnorm<<<NTOK, 384, 0, stream>>>(x_f32, g_f32, xn);
  k_gemm_bt<false><<<32*(QKVN/128), 256, 0, stream>>>(xn, wqkvb, qkv, nullptr, QKVN, HID);
  k_rope_vt<<<ROPE_BLOCKS + VT_BLOCKS, 256, 0, stream>>>(qkv, qbuf, kbuf, vtb, spp);
  k_attn<<<B_*NQ_*(S_/32), 64, 0, stream>>>(qbuf, kbuf, vtb, attn, spp);
  k_gemm_bt<true><<<32*(HID/128), 256, 0, stream>>>(attn, woutb, d_out, x_f32, HID, HID);
}